// Round 2
// baseline (2391.025 us; speedup 1.0000x reference)
//
#include <hip/hip_runtime.h>

// ---------------------------------------------------------------------------
// GCN block, bucket-partitioned aggregation (no per-node CSR).
//   norm(src,dst) = dinv[src]*dinv[dst]; dinv[src] folded into GEMM epilogue,
//   dinv[dst] folded into aggregation epilogue.
//   Edges partitioned once per call by bucket = dst>>8 (256 nodes/bucket).
//   Aggregation: one block per bucket, 256x64 f32 accumulator tile in LDS
//   (64 KB), ds_add_f32 atomics (bank-conflict-free), coalesced streaming of
//   4-byte packed entries (src<<8 | dst&255).
// ---------------------------------------------------------------------------

#define LB 8                    // low bits: 256 nodes per bucket
#define BKN 256                 // nodes per bucket
#define CHUNK 8192              // edges per scatter block

// ---- edge dtype detection (int64 vs int32) --------------------------------
__global__ void detect64_kernel(const unsigned int* __restrict__ raw, int nwords,
                                int* __restrict__ flag) {
    int stride = gridDim.x * blockDim.x;
    for (int i = blockIdx.x * blockDim.x + threadIdx.x; i < nwords; i += stride)
        if ((i & 1) && raw[i] != 0u) flag[0] = 0; // benign race
}

__global__ void convert_idx_kernel(const int* __restrict__ raw, int* __restrict__ out,
                                   int n, const int* __restrict__ flag) {
    int i = blockIdx.x * blockDim.x + threadIdx.x;
    if (i >= n) return;
    out[i] = flag[0] ? raw[2 * i] : raw[i];   // int64 little-endian low word
}

// ---- bucket histogram ------------------------------------------------------
__global__ __launch_bounds__(256) void bucket_hist_kernel(
        const int* __restrict__ dst, int E, int* __restrict__ bucketCounts, int B) {
    __shared__ int h[512];
    for (int i = threadIdx.x; i < 512; i += 256) h[i] = 0;
    __syncthreads();
    int stride = gridDim.x * blockDim.x;
    for (int e = blockIdx.x * blockDim.x + threadIdx.x; e < E; e += stride)
        atomicAdd(&h[dst[e] >> LB], 1);
    __syncthreads();
    for (int i = threadIdx.x; i < B; i += 256)
        if (h[i]) atomicAdd(&bucketCounts[i], h[i]);
}

// ---- bucket exclusive scan (B <= 512), writes offs + cursor copy ----------
__global__ __launch_bounds__(512) void bucket_scan_kernel(
        const int* __restrict__ counts, int* __restrict__ offs,
        int* __restrict__ cursor, int B) {
    __shared__ int s[512];
    int tid = threadIdx.x;
    int v = (tid < B) ? counts[tid] : 0;
    s[tid] = v;
    __syncthreads();
    for (int off = 1; off < 512; off <<= 1) {
        int x = (tid >= off) ? s[tid - off] : 0;
        __syncthreads();
        if (tid >= off) s[tid] += x;
        __syncthreads();
    }
    if (tid < B) { int e = s[tid] - v; offs[tid] = e; cursor[tid] = e; }
    if (tid == B - 1) offs[B] = s[tid];
}

// ---- partition edges into bucket regions as packed (src<<8 | dst&255) -----
__global__ __launch_bounds__(256) void bucket_scatter_kernel(
        const int* __restrict__ src, const int* __restrict__ dst,
        int* __restrict__ bucketCursor, unsigned int* __restrict__ packed, int E) {
    __shared__ int hist[512];
    __shared__ int base[512];
    int b0 = blockIdx.x * CHUNK;
    int n = min(CHUNK, E - b0);
    for (int i = threadIdx.x; i < 512; i += 256) hist[i] = 0;
    __syncthreads();
    for (int i = threadIdx.x; i < n; i += 256)
        atomicAdd(&hist[dst[b0 + i] >> LB], 1);
    __syncthreads();
    for (int i = threadIdx.x; i < 512; i += 256) {
        int c = hist[i];
        base[i] = c ? atomicAdd(&bucketCursor[i], c) : 0;
        hist[i] = 0;
    }
    __syncthreads();
    for (int i = threadIdx.x; i < n; i += 256) {
        int d = dst[b0 + i], s = src[b0 + i];
        int bk = d >> LB;
        int pos = base[bk] + atomicAdd(&hist[bk], 1);
        packed[pos] = ((unsigned)s << LB) | (unsigned)(d & (BKN - 1));
    }
}

// ---- per-node degree -> dinv, per bucket (LDS histogram) ------------------
__global__ __launch_bounds__(256) void dinv_kernel(
        const unsigned int* __restrict__ packed, const int* __restrict__ offs,
        float* __restrict__ dinv, int N) {
    __shared__ int cnt[BKN];
    cnt[threadIdx.x] = 0;
    __syncthreads();
    int b = blockIdx.x;
    int start = offs[b], end = offs[b + 1];
    for (int e = start + threadIdx.x; e < end; e += 256)
        atomicAdd(&cnt[packed[e] & (BKN - 1)], 1);
    __syncthreads();
    int node = (b << LB) + threadIdx.x;
    if (node < N) dinv[node] = rsqrtf((float)(cnt[threadIdx.x] + 1)); // +1 self loop
}

// ---- GEMM (N x K) @ (K x 64), epilogue-scaled by dinv[row] ----------------
template <int K>
__global__ __launch_bounds__(256) void gemm_scaled_kernel(
        const float* __restrict__ A, const float* __restrict__ W,
        const float* __restrict__ dinv, float* __restrict__ out, int nrows) {
    __shared__ float sW[K * 64];
    __shared__ float sX[32 * 256];
    int tid = threadIdx.x;
    int rowBase = blockIdx.x * 256;
    for (int i = tid * 4; i < K * 64; i += 1024)
        *(float4*)&sW[i] = *(const float4*)&W[i];
    int c0 = (tid & 7) * 8;
    int r0 = (tid >> 3) * 8;
    float acc[8][8];
#pragma unroll
    for (int r = 0; r < 8; r++)
#pragma unroll
        for (int c = 0; c < 8; c++) acc[r][c] = 0.f;

    for (int kb = 0; kb < K; kb += 32) {
        __syncthreads();
        {
            int row = tid;
            int grow = rowBase + row;
            if (grow >= nrows) grow = nrows - 1;
            const float* srcp = A + (size_t)grow * K + kb;
#pragma unroll
            for (int j = 0; j < 8; j++) {
                float4 v = *(const float4*)(srcp + j * 4);
                sX[(j * 4 + 0) * 256 + row] = v.x;
                sX[(j * 4 + 1) * 256 + row] = v.y;
                sX[(j * 4 + 2) * 256 + row] = v.z;
                sX[(j * 4 + 3) * 256 + row] = v.w;
            }
        }
        __syncthreads();
#pragma unroll
        for (int k = 0; k < 32; k++) {
            float xv[8], wv[8];
            *(float4*)&xv[0] = *(float4*)&sX[k * 256 + r0];
            *(float4*)&xv[4] = *(float4*)&sX[k * 256 + r0 + 4];
            *(float4*)&wv[0] = *(float4*)&sW[(kb + k) * 64 + c0];
            *(float4*)&wv[4] = *(float4*)&sW[(kb + k) * 64 + c0 + 4];
#pragma unroll
            for (int r = 0; r < 8; r++)
#pragma unroll
                for (int c = 0; c < 8; c++)
                    acc[r][c] = fmaf(xv[r], wv[c], acc[r][c]);
        }
    }
#pragma unroll
    for (int r = 0; r < 8; r++) {
        int grow = rowBase + r0 + r;
        if (grow < nrows) {
            float sc = dinv[grow];
            float4 o0 = make_float4(acc[r][0] * sc, acc[r][1] * sc, acc[r][2] * sc, acc[r][3] * sc);
            float4 o1 = make_float4(acc[r][4] * sc, acc[r][5] * sc, acc[r][6] * sc, acc[r][7] * sc);
            *(float4*)&out[(size_t)grow * 64 + c0] = o0;
            *(float4*)&out[(size_t)grow * 64 + c0 + 4] = o1;
        }
    }
}

// ---- aggregation: one block per bucket, 256x64 LDS accumulator ------------
// out[n] = dinv[n] * (hs[n] + sum_{e: dst=n} hs[src_e]) + bias  (+relu,+resid)
__global__ __launch_bounds__(256) void aggregate_kernel(
        const float* __restrict__ hs, const float* __restrict__ dinv,
        const float* __restrict__ bias, const unsigned int* __restrict__ packed,
        const int* __restrict__ offs, const float* __restrict__ resid,
        float* __restrict__ out, int N, int relu) {
    __shared__ float acc[BKN * 64];   // 64 KB
    int b = blockIdx.x;
    int nodeBase = b << LB;
    int nvalid = min(BKN, N - nodeBase);
    // init with self-loop term hs[node] (already scaled by dinv[node])
    for (int i = threadIdx.x * 4; i < BKN * 64; i += 1024) {
        int d = i >> 6;
        if (d < nvalid)
            *(float4*)&acc[i] = *(const float4*)&hs[(size_t)(nodeBase + d) * 64 + (i & 63)];
        else
            *(float4*)&acc[i] = make_float4(0.f, 0.f, 0.f, 0.f);
    }
    __syncthreads();
    int start = offs[b], end = offs[b + 1];
    int wave = threadIdx.x >> 6, lane = threadIdx.x & 63;
    for (int e = start + wave * 64; e < end; e += 256) {
        int cnt = min(64, end - e);
        unsigned int myv = (lane < cnt) ? packed[e + lane] : 0u;
        int j = 0;
        for (; j + 4 <= cnt; j += 4) {
            unsigned v0 = __shfl(myv, j + 0);
            unsigned v1 = __shfl(myv, j + 1);
            unsigned v2 = __shfl(myv, j + 2);
            unsigned v3 = __shfl(myv, j + 3);
            float f0 = hs[(size_t)(v0 >> LB) * 64 + lane];
            float f1 = hs[(size_t)(v1 >> LB) * 64 + lane];
            float f2 = hs[(size_t)(v2 >> LB) * 64 + lane];
            float f3 = hs[(size_t)(v3 >> LB) * 64 + lane];
            atomicAdd(&acc[((v0 & (BKN - 1)) << 6) + lane], f0);
            atomicAdd(&acc[((v1 & (BKN - 1)) << 6) + lane], f1);
            atomicAdd(&acc[((v2 & (BKN - 1)) << 6) + lane], f2);
            atomicAdd(&acc[((v3 & (BKN - 1)) << 6) + lane], f3);
        }
        for (; j < cnt; j++) {
            unsigned v = __shfl(myv, j);
            atomicAdd(&acc[((v & (BKN - 1)) << 6) + lane], hs[(size_t)(v >> LB) * 64 + lane]);
        }
    }
    __syncthreads();
    // epilogue
    for (int i = threadIdx.x * 4; i < BKN * 64; i += 1024) {
        int d = i >> 6;
        if (d >= nvalid) continue;
        int node = nodeBase + d;
        int c = i & 63;
        float sc = dinv[node];
        float4 a = *(float4*)&acc[i];
        float4 o;
        o.x = sc * a.x + bias[c + 0];
        o.y = sc * a.y + bias[c + 1];
        o.z = sc * a.z + bias[c + 2];
        o.w = sc * a.w + bias[c + 3];
        if (relu) {
            o.x = fmaxf(o.x, 0.f); o.y = fmaxf(o.y, 0.f);
            o.z = fmaxf(o.z, 0.f); o.w = fmaxf(o.w, 0.f);
        }
        if (resid) {
            float4 r = *(const float4*)&resid[(size_t)node * 64 + c];
            o.x += r.x; o.y += r.y; o.z += r.z; o.w += r.w;
        }
        *(float4*)&out[(size_t)node * 64 + c] = o;
    }
}

// ---------------------------------------------------------------------------
extern "C" void kernel_launch(void* const* d_in, const int* in_sizes, int n_in,
                              void* d_out, int out_size, void* d_ws, size_t ws_size,
                              hipStream_t stream) {
    const float* x  = (const float*)d_in[0];
    const int*   ei = (const int*)d_in[1];
    const float* W0 = (const float*)d_in[2];
    const float* b0 = (const float*)d_in[3];
    const float* Ws = (const float*)d_in[4];
    const float* bs = (const float*)d_in[5];
    float* out = (float*)d_out;

    const int N = in_sizes[0] / 128;
    const int E = in_sizes[1] / 2;
    const int B = (N + BKN - 1) >> LB;   // 391 buckets for N=100k

    char* p = (char*)d_ws;
    auto carve = [&](size_t bytes) {
        char* r = p;
        p += (bytes + 255) & ~(size_t)255;
        return r;
    };
    int*      flag         = (int*)carve(4);
    int*      idx32        = (int*)carve((size_t)2 * E * 4);
    int*      bucketCounts = (int*)carve(512 * 4);
    int*      bucketOffs   = (int*)carve(513 * 4);
    int*      bucketCursor = (int*)carve(512 * 4);
    unsigned* packed       = (unsigned*)carve((size_t)E * 4);
    float*    dinv         = (float*)carve((size_t)N * 4);
    float*    hs           = (float*)carve((size_t)N * 64 * 4);
    float*    xt           = (float*)carve((size_t)N * 64 * 4);
    float*    h            = (float*)carve((size_t)N * 64 * 4);

    hipMemsetAsync(flag, 1, 4, stream);              // nonzero = "int64"
    hipMemsetAsync(bucketCounts, 0, 512 * 4, stream);

    detect64_kernel<<<512, 256, 0, stream>>>((const unsigned int*)ei, 2 * E, flag);
    convert_idx_kernel<<<(2 * E + 255) / 256, 256, 0, stream>>>(ei, idx32, 2 * E, flag);
    const int* src = idx32;
    const int* dst = idx32 + E;

    bucket_hist_kernel<<<512, 256, 0, stream>>>(dst, E, bucketCounts, B);
    bucket_scan_kernel<<<1, 512, 0, stream>>>(bucketCounts, bucketOffs, bucketCursor, B);
    bucket_scatter_kernel<<<(E + CHUNK - 1) / CHUNK, 256, 0, stream>>>(
        src, dst, bucketCursor, packed, E);
    dinv_kernel<<<B, 256, 0, stream>>>(packed, bucketOffs, dinv, N);

    int gblocks = (N + 255) / 256;
    // layer 1: x_temp = agg(x @ W0) + b0            (no relu)
    gemm_scaled_kernel<128><<<gblocks, 256, 0, stream>>>(x, W0, dinv, hs, N);
    aggregate_kernel<<<B, 256, 0, stream>>>(hs, dinv, b0, packed, bucketOffs, nullptr, xt, N, 0);
    // layer 2: h = relu(agg(xt @ Ws[0]) + bs[0])
    gemm_scaled_kernel<64><<<gblocks, 256, 0, stream>>>(xt, Ws, dinv, hs, N);
    aggregate_kernel<<<B, 256, 0, stream>>>(hs, dinv, bs, packed, bucketOffs, nullptr, h, N, 1);
    // layer 3: out = relu(agg(h @ Ws[1]) + bs[1]) + xt
    gemm_scaled_kernel<64><<<gblocks, 256, 0, stream>>>(h, Ws + 64 * 64, dinv, hs, N);
    aggregate_kernel<<<B, 256, 0, stream>>>(hs, dinv, bs + 64, packed, bucketOffs, xt, out, N, 1);
}

// Round 3
// 441.792 us; speedup vs baseline: 5.4121x; 5.4121x over previous
//
#include <hip/hip_runtime.h>

// ---------------------------------------------------------------------------
// GCN block: 3x (GEMM -> degree-normalized aggregate), residual, relu.
//   norm(src,dst) = dinv[src]*dinv[dst]; dinv[src] folded into GEMM epilogue,
//   dinv[dst] folded into aggregation epilogue.
// CSR build without write amplification:
//   1) bucket partition edges by dst>>8 into packed (src<<8 | dst&255)
//      (runs of ~21 entries -> L2 write-combines)
//   2) per-bucket LDS counting sort -> node-level CSR col[] written into a
//      contiguous ~16KB window per bucket (L2-resident), plus row_ptr + dinv
// Aggregation: one wave per node (100k waves -> full occupancy), lane=col,
//   neighbor indices broadcast via __shfl, 256B coalesced row gathers.
// ---------------------------------------------------------------------------

#define LB 8                    // low bits: 256 nodes per bucket
#define BKN 256                 // nodes per bucket
#define CHUNK 8192              // edges per scatter block

// ---- edge dtype detection (int64 vs int32) --------------------------------
__global__ void detect64_kernel(const unsigned int* __restrict__ raw, int nwords,
                                int* __restrict__ flag) {
    int stride = gridDim.x * blockDim.x;
    for (int i = blockIdx.x * blockDim.x + threadIdx.x; i < nwords; i += stride)
        if ((i & 1) && raw[i] != 0u) flag[0] = 0; // benign race
}

__global__ void convert_idx_kernel(const int* __restrict__ raw, int* __restrict__ out,
                                   int n, const int* __restrict__ flag) {
    int i = blockIdx.x * blockDim.x + threadIdx.x;
    if (i >= n) return;
    out[i] = flag[0] ? raw[2 * i] : raw[i];   // int64 little-endian low word
}

// ---- bucket histogram ------------------------------------------------------
__global__ __launch_bounds__(256) void bucket_hist_kernel(
        const int* __restrict__ dst, int E, int* __restrict__ bucketCounts, int B) {
    __shared__ int h[512];
    for (int i = threadIdx.x; i < 512; i += 256) h[i] = 0;
    __syncthreads();
    int stride = gridDim.x * blockDim.x;
    for (int e = blockIdx.x * blockDim.x + threadIdx.x; e < E; e += stride)
        atomicAdd(&h[dst[e] >> LB], 1);
    __syncthreads();
    for (int i = threadIdx.x; i < B; i += 256)
        if (h[i]) atomicAdd(&bucketCounts[i], h[i]);
}

// ---- bucket exclusive scan (B <= 512), writes offs + cursor copy ----------
__global__ __launch_bounds__(512) void bucket_scan_kernel(
        const int* __restrict__ counts, int* __restrict__ offs,
        int* __restrict__ cursor, int B) {
    __shared__ int s[512];
    int tid = threadIdx.x;
    int v = (tid < B) ? counts[tid] : 0;
    s[tid] = v;
    __syncthreads();
    for (int off = 1; off < 512; off <<= 1) {
        int x = (tid >= off) ? s[tid - off] : 0;
        __syncthreads();
        if (tid >= off) s[tid] += x;
        __syncthreads();
    }
    if (tid < B) { int e = s[tid] - v; offs[tid] = e; cursor[tid] = e; }
    if (tid == B - 1) offs[B] = s[tid];
}

// ---- partition edges into bucket regions as packed (src<<8 | dst&255) -----
__global__ __launch_bounds__(256) void bucket_scatter_kernel(
        const int* __restrict__ src, const int* __restrict__ dst,
        int* __restrict__ bucketCursor, unsigned int* __restrict__ packed, int E) {
    __shared__ int hist[512];
    __shared__ int base[512];
    int b0 = blockIdx.x * CHUNK;
    int n = min(CHUNK, E - b0);
    for (int i = threadIdx.x; i < 512; i += 256) hist[i] = 0;
    __syncthreads();
    for (int i = threadIdx.x; i < n; i += 256)
        atomicAdd(&hist[dst[b0 + i] >> LB], 1);
    __syncthreads();
    for (int i = threadIdx.x; i < 512; i += 256) {
        int c = hist[i];
        base[i] = c ? atomicAdd(&bucketCursor[i], c) : 0;
        hist[i] = 0;
    }
    __syncthreads();
    for (int i = threadIdx.x; i < n; i += 256) {
        int d = dst[b0 + i], s = src[b0 + i];
        int bk = d >> LB;
        int pos = base[bk] + atomicAdd(&hist[bk], 1);
        packed[pos] = ((unsigned)s << LB) | (unsigned)(d & (BKN - 1));
    }
}

// ---- per-bucket counting sort: packed -> CSR col[], row_ptr, dinv ---------
__global__ __launch_bounds__(256) void sort_kernel(
        const unsigned int* __restrict__ packed, const int* __restrict__ offs,
        int* __restrict__ col, int* __restrict__ row_ptr, float* __restrict__ dinv,
        int N, int E) {
    __shared__ int hist[BKN];
    __shared__ int s[BKN];
    __shared__ int cur[BKN];
    int tid = threadIdx.x;
    int b = blockIdx.x;
    int start = offs[b], end = offs[b + 1];
    hist[tid] = 0;
    __syncthreads();
    for (int e = start + tid; e < end; e += 256)
        atomicAdd(&hist[packed[e] & (BKN - 1)], 1);
    __syncthreads();
    int v = hist[tid];
    s[tid] = v;
    __syncthreads();
    for (int off = 1; off < 256; off <<= 1) {
        int x = (tid >= off) ? s[tid - off] : 0;
        __syncthreads();
        if (tid >= off) s[tid] += x;
        __syncthreads();
    }
    int excl = s[tid] - v;
    cur[tid] = start + excl;
    int node = (b << LB) + tid;
    if (node < N) {
        row_ptr[node] = start + excl;
        dinv[node] = rsqrtf((float)(v + 1));   // +1 self loop
    }
    if (b == 0 && tid == 0) row_ptr[N] = E;
    __syncthreads();
    for (int e = start + tid; e < end; e += 256) {
        unsigned pv = packed[e];
        int pos = atomicAdd(&cur[pv & (BKN - 1)], 1);
        col[pos] = (int)(pv >> LB);
    }
}

// ---- GEMM (N x K) @ (K x 64), epilogue-scaled by dinv[row] ----------------
template <int K>
__global__ __launch_bounds__(256) void gemm_scaled_kernel(
        const float* __restrict__ A, const float* __restrict__ W,
        const float* __restrict__ dinv, float* __restrict__ out, int nrows) {
    __shared__ float sW[K * 64];
    __shared__ float sX[32 * 256];
    int tid = threadIdx.x;
    int rowBase = blockIdx.x * 256;
    for (int i = tid * 4; i < K * 64; i += 1024)
        *(float4*)&sW[i] = *(const float4*)&W[i];
    int c0 = (tid & 7) * 8;
    int r0 = (tid >> 3) * 8;
    float acc[8][8];
#pragma unroll
    for (int r = 0; r < 8; r++)
#pragma unroll
        for (int c = 0; c < 8; c++) acc[r][c] = 0.f;

    for (int kb = 0; kb < K; kb += 32) {
        __syncthreads();
        {
            int row = tid;
            int grow = rowBase + row;
            if (grow >= nrows) grow = nrows - 1;
            const float* srcp = A + (size_t)grow * K + kb;
#pragma unroll
            for (int j = 0; j < 8; j++) {
                float4 v = *(const float4*)(srcp + j * 4);
                sX[(j * 4 + 0) * 256 + row] = v.x;
                sX[(j * 4 + 1) * 256 + row] = v.y;
                sX[(j * 4 + 2) * 256 + row] = v.z;
                sX[(j * 4 + 3) * 256 + row] = v.w;
            }
        }
        __syncthreads();
#pragma unroll
        for (int k = 0; k < 32; k++) {
            float xv[8], wv[8];
            *(float4*)&xv[0] = *(float4*)&sX[k * 256 + r0];
            *(float4*)&xv[4] = *(float4*)&sX[k * 256 + r0 + 4];
            *(float4*)&wv[0] = *(float4*)&sW[(kb + k) * 64 + c0];
            *(float4*)&wv[4] = *(float4*)&sW[(kb + k) * 64 + c0 + 4];
#pragma unroll
            for (int r = 0; r < 8; r++)
#pragma unroll
                for (int c = 0; c < 8; c++)
                    acc[r][c] = fmaf(xv[r], wv[c], acc[r][c]);
        }
    }
#pragma unroll
    for (int r = 0; r < 8; r++) {
        int grow = rowBase + r0 + r;
        if (grow < nrows) {
            float sc = dinv[grow];
            float4 o0 = make_float4(acc[r][0] * sc, acc[r][1] * sc, acc[r][2] * sc, acc[r][3] * sc);
            float4 o1 = make_float4(acc[r][4] * sc, acc[r][5] * sc, acc[r][6] * sc, acc[r][7] * sc);
            *(float4*)&out[(size_t)grow * 64 + c0] = o0;
            *(float4*)&out[(size_t)grow * 64 + c0 + 4] = o1;
        }
    }
}

// ---- aggregation: one wave per node, lane = feature column ----------------
// out[n] = dinv[n] * (hs[n] + sum_{e in adj(n)} hs[col[e]]) + bias
// (+ optional relu, optional residual add)
__global__ __launch_bounds__(256) void aggregate_kernel(
        const float* __restrict__ hs, const float* __restrict__ dinv,
        const float* __restrict__ bias, const int* __restrict__ col,
        const int* __restrict__ row_ptr, const float* __restrict__ resid,
        float* __restrict__ out, int n, int relu) {
    int wave = (blockIdx.x * blockDim.x + threadIdx.x) >> 6;
    int lane = threadIdx.x & 63;
    if (wave >= n) return;
    int start = row_ptr[wave];
    int end = row_ptr[wave + 1];
    float acc = hs[(size_t)wave * 64 + lane]; // self-loop term (pre-scaled)
    int e = start;
    while (e < end) {
        int cnt = end - e;
        if (cnt > 64) cnt = 64;
        int myidx = (lane < cnt) ? col[e + lane] : 0;
        int j = 0;
        for (; j + 4 <= cnt; j += 4) {
            int s0 = __shfl(myidx, j + 0);
            int s1 = __shfl(myidx, j + 1);
            int s2 = __shfl(myidx, j + 2);
            int s3 = __shfl(myidx, j + 3);
            float v0 = hs[(size_t)s0 * 64 + lane];
            float v1 = hs[(size_t)s1 * 64 + lane];
            float v2 = hs[(size_t)s2 * 64 + lane];
            float v3 = hs[(size_t)s3 * 64 + lane];
            acc += v0 + v1 + v2 + v3;
        }
        for (; j < cnt; j++) {
            int s = __shfl(myidx, j);
            acc += hs[(size_t)s * 64 + lane];
        }
        e += cnt;
    }
    float o = dinv[wave] * acc + bias[lane];
    if (relu) o = fmaxf(o, 0.f);
    if (resid) o += resid[(size_t)wave * 64 + lane];
    out[(size_t)wave * 64 + lane] = o;
}

// ---------------------------------------------------------------------------
extern "C" void kernel_launch(void* const* d_in, const int* in_sizes, int n_in,
                              void* d_out, int out_size, void* d_ws, size_t ws_size,
                              hipStream_t stream) {
    const float* x  = (const float*)d_in[0];
    const int*   ei = (const int*)d_in[1];
    const float* W0 = (const float*)d_in[2];
    const float* b0 = (const float*)d_in[3];
    const float* Ws = (const float*)d_in[4];
    const float* bs = (const float*)d_in[5];
    float* out = (float*)d_out;

    const int N = in_sizes[0] / 128;
    const int E = in_sizes[1] / 2;
    const int B = (N + BKN - 1) >> LB;   // 391 buckets for N=100k

    char* p = (char*)d_ws;
    auto carve = [&](size_t bytes) {
        char* r = p;
        p += (bytes + 255) & ~(size_t)255;
        return r;
    };
    int*      flag         = (int*)carve(4);
    int*      idx32        = (int*)carve((size_t)2 * E * 4);
    int*      bucketCounts = (int*)carve(512 * 4);
    int*      bucketOffs   = (int*)carve(513 * 4);
    int*      bucketCursor = (int*)carve(512 * 4);
    unsigned* packed       = (unsigned*)carve((size_t)E * 4);
    int*      col          = (int*)carve((size_t)E * 4);
    int*      row_ptr      = (int*)carve((size_t)(N + 1) * 4);
    float*    dinv         = (float*)carve((size_t)N * 4);
    float*    hs           = (float*)carve((size_t)N * 64 * 4);
    float*    xt           = (float*)carve((size_t)N * 64 * 4);
    float*    h            = (float*)carve((size_t)N * 64 * 4);

    hipMemsetAsync(flag, 1, 4, stream);              // nonzero = "int64"
    hipMemsetAsync(bucketCounts, 0, 512 * 4, stream);

    detect64_kernel<<<512, 256, 0, stream>>>((const unsigned int*)ei, 2 * E, flag);
    convert_idx_kernel<<<(2 * E + 255) / 256, 256, 0, stream>>>(ei, idx32, 2 * E, flag);
    const int* src = idx32;
    const int* dst = idx32 + E;

    bucket_hist_kernel<<<512, 256, 0, stream>>>(dst, E, bucketCounts, B);
    bucket_scan_kernel<<<1, 512, 0, stream>>>(bucketCounts, bucketOffs, bucketCursor, B);
    bucket_scatter_kernel<<<(E + CHUNK - 1) / CHUNK, 256, 0, stream>>>(
        src, dst, bucketCursor, packed, E);
    sort_kernel<<<B, 256, 0, stream>>>(packed, bucketOffs, col, row_ptr, dinv, N, E);

    int gblocks = (N + 255) / 256;
    int ablocks = (N + 3) / 4;
    // layer 1: x_temp = agg(x @ W0) + b0            (no relu)
    gemm_scaled_kernel<128><<<gblocks, 256, 0, stream>>>(x, W0, dinv, hs, N);
    aggregate_kernel<<<ablocks, 256, 0, stream>>>(hs, dinv, b0, col, row_ptr, nullptr, xt, N, 0);
    // layer 2: h = relu(agg(xt @ Ws[0]) + bs[0])
    gemm_scaled_kernel<64><<<gblocks, 256, 0, stream>>>(xt, Ws, dinv, hs, N);
    aggregate_kernel<<<ablocks, 256, 0, stream>>>(hs, dinv, bs, col, row_ptr, nullptr, h, N, 1);
    // layer 3: out = relu(agg(h @ Ws[1]) + bs[1]) + xt
    gemm_scaled_kernel<64><<<gblocks, 256, 0, stream>>>(h, Ws + 64 * 64, dinv, hs, N);
    aggregate_kernel<<<ablocks, 256, 0, stream>>>(hs, dinv, bs + 64, col, row_ptr, xt, out, N, 1);
}

// Round 4
// 407.220 us; speedup vs baseline: 5.8716x; 1.0849x over previous
//
#include <hip/hip_runtime.h>

// ---------------------------------------------------------------------------
// GCN block: 3x (GEMM -> degree-normalized aggregate), residual, relu.
//   norm(src,dst) = dinv[src]*dinv[dst]; dinv[src] folded into GEMM epilogue,
//   dinv[dst] folded into aggregation epilogue.
//   hs (the gathered tensor) is stored bf16 -> halves the random-gather bytes.
// CSR build: bucket partition by dst>>8 (packed src<<8|dst&255), then
//   per-bucket LDS counting sort -> node CSR col[] in a contiguous L2-resident
//   window, row_ptr + dinv for free. No int64->int32 conversion pass: hist &
//   scatter read the raw edge_index with a flag-dependent stride.
// Aggregation: one wave per node, lane = feature col, indices via __shfl.
// ---------------------------------------------------------------------------

#define LB 8                    // low bits: 256 nodes per bucket
#define BKN 256                 // nodes per bucket
#define CHUNK 8192              // edges per scatter block

typedef unsigned short ushort_t;

__device__ __forceinline__ ushort_t f2bf(float f) {
    unsigned u = __builtin_bit_cast(unsigned, f);
    unsigned r = (u + 0x7FFFu + ((u >> 16) & 1u)) >> 16;   // RNE
    return (ushort_t)r;
}
__device__ __forceinline__ float bf2f(ushort_t h) {
    unsigned u = ((unsigned)h) << 16;
    return __builtin_bit_cast(float, u);
}

// ---- edge dtype detection (int64 vs int32), sampled -----------------------
__global__ void detect64_kernel(const unsigned int* __restrict__ raw, int nwords,
                                int* __restrict__ flag) {
    int i = blockIdx.x * blockDim.x + threadIdx.x;
    if (i < nwords && (i & 1) && raw[i] != 0u) flag[0] = 0; // benign race
}

// ---- bucket histogram (reads raw dst) -------------------------------------
__global__ __launch_bounds__(256) void bucket_hist_kernel(
        const int* __restrict__ raw, int E, const int* __restrict__ flag,
        int* __restrict__ bucketCounts, int B) {
    __shared__ int h[512];
    for (int i = threadIdx.x; i < 512; i += 256) h[i] = 0;
    __syncthreads();
    int f = flag[0];
    int stride = gridDim.x * blockDim.x;
    for (int e = blockIdx.x * blockDim.x + threadIdx.x; e < E; e += stride) {
        int d = f ? raw[2 * (E + e)] : raw[E + e];
        atomicAdd(&h[d >> LB], 1);
    }
    __syncthreads();
    for (int i = threadIdx.x; i < B; i += 256)
        if (h[i]) atomicAdd(&bucketCounts[i], h[i]);
}

// ---- bucket exclusive scan (B <= 512), writes offs + cursor copy ----------
__global__ __launch_bounds__(512) void bucket_scan_kernel(
        const int* __restrict__ counts, int* __restrict__ offs,
        int* __restrict__ cursor, int B) {
    __shared__ int s[512];
    int tid = threadIdx.x;
    int v = (tid < B) ? counts[tid] : 0;
    s[tid] = v;
    __syncthreads();
    for (int off = 1; off < 512; off <<= 1) {
        int x = (tid >= off) ? s[tid - off] : 0;
        __syncthreads();
        if (tid >= off) s[tid] += x;
        __syncthreads();
    }
    if (tid < B) { int e = s[tid] - v; offs[tid] = e; cursor[tid] = e; }
    if (tid == B - 1) offs[B] = s[tid];
}

// ---- partition edges into bucket regions as packed (src<<8 | dst&255) -----
__global__ __launch_bounds__(256) void bucket_scatter_kernel(
        const int* __restrict__ raw, const int* __restrict__ flag,
        int* __restrict__ bucketCursor, unsigned int* __restrict__ packed, int E) {
    __shared__ int hist[512];
    __shared__ int base[512];
    int f = flag[0];
    int b0 = blockIdx.x * CHUNK;
    int n = min(CHUNK, E - b0);
    for (int i = threadIdx.x; i < 512; i += 256) hist[i] = 0;
    __syncthreads();
    for (int i = threadIdx.x; i < n; i += 256) {
        int e = b0 + i;
        int d = f ? raw[2 * (E + e)] : raw[E + e];
        atomicAdd(&hist[d >> LB], 1);
    }
    __syncthreads();
    for (int i = threadIdx.x; i < 512; i += 256) {
        int c = hist[i];
        base[i] = c ? atomicAdd(&bucketCursor[i], c) : 0;
        hist[i] = 0;
    }
    __syncthreads();
    for (int i = threadIdx.x; i < n; i += 256) {
        int e = b0 + i;
        int d = f ? raw[2 * (E + e)] : raw[E + e];
        int s = f ? raw[2 * e] : raw[e];
        int bk = d >> LB;
        int pos = base[bk] + atomicAdd(&hist[bk], 1);
        packed[pos] = ((unsigned)s << LB) | (unsigned)(d & (BKN - 1));
    }
}

// ---- per-bucket counting sort: packed -> CSR col[], row_ptr, dinv ---------
__global__ __launch_bounds__(256) void sort_kernel(
        const unsigned int* __restrict__ packed, const int* __restrict__ offs,
        int* __restrict__ col, int* __restrict__ row_ptr, float* __restrict__ dinv,
        int N, int E) {
    __shared__ int hist[BKN];
    __shared__ int s[BKN];
    __shared__ int cur[BKN];
    int tid = threadIdx.x;
    int b = blockIdx.x;
    int start = offs[b], end = offs[b + 1];
    hist[tid] = 0;
    __syncthreads();
    for (int e = start + tid; e < end; e += 256)
        atomicAdd(&hist[packed[e] & (BKN - 1)], 1);
    __syncthreads();
    int v = hist[tid];
    s[tid] = v;
    __syncthreads();
    for (int off = 1; off < 256; off <<= 1) {
        int x = (tid >= off) ? s[tid - off] : 0;
        __syncthreads();
        if (tid >= off) s[tid] += x;
        __syncthreads();
    }
    int excl = s[tid] - v;
    cur[tid] = start + excl;
    int node = (b << LB) + tid;
    if (node < N) {
        row_ptr[node] = start + excl;
        dinv[node] = rsqrtf((float)(v + 1));   // +1 self loop
    }
    if (b == 0 && tid == 0) row_ptr[N] = E;
    __syncthreads();
    for (int e = start + tid; e < end; e += 256) {
        unsigned pv = packed[e];
        int pos = atomicAdd(&cur[pv & (BKN - 1)], 1);
        col[pos] = (int)(pv >> LB);
    }
}

// ---- GEMM (N x K) @ (K x 64), epilogue-scaled by dinv[row], bf16 out ------
template <int K>
__global__ __launch_bounds__(256) void gemm_scaled_kernel(
        const float* __restrict__ A, const float* __restrict__ W,
        const float* __restrict__ dinv, ushort_t* __restrict__ out, int nrows) {
    __shared__ float sW[K * 64];
    __shared__ float sX[32 * 256];
    int tid = threadIdx.x;
    int rowBase = blockIdx.x * 256;
    for (int i = tid * 4; i < K * 64; i += 1024)
        *(float4*)&sW[i] = *(const float4*)&W[i];
    int c0 = (tid & 7) * 8;
    int r0 = (tid >> 3) * 8;
    float acc[8][8];
#pragma unroll
    for (int r = 0; r < 8; r++)
#pragma unroll
        for (int c = 0; c < 8; c++) acc[r][c] = 0.f;

    for (int kb = 0; kb < K; kb += 32) {
        __syncthreads();
        {
            int row = tid;
            int grow = rowBase + row;
            if (grow >= nrows) grow = nrows - 1;
            const float* srcp = A + (size_t)grow * K + kb;
#pragma unroll
            for (int j = 0; j < 8; j++) {
                float4 v = *(const float4*)(srcp + j * 4);
                sX[(j * 4 + 0) * 256 + row] = v.x;
                sX[(j * 4 + 1) * 256 + row] = v.y;
                sX[(j * 4 + 2) * 256 + row] = v.z;
                sX[(j * 4 + 3) * 256 + row] = v.w;
            }
        }
        __syncthreads();
#pragma unroll
        for (int k = 0; k < 32; k++) {
            float xv[8], wv[8];
            *(float4*)&xv[0] = *(float4*)&sX[k * 256 + r0];
            *(float4*)&xv[4] = *(float4*)&sX[k * 256 + r0 + 4];
            *(float4*)&wv[0] = *(float4*)&sW[(kb + k) * 64 + c0];
            *(float4*)&wv[4] = *(float4*)&sW[(kb + k) * 64 + c0 + 4];
#pragma unroll
            for (int r = 0; r < 8; r++)
#pragma unroll
                for (int c = 0; c < 8; c++)
                    acc[r][c] = fmaf(xv[r], wv[c], acc[r][c]);
        }
    }
#pragma unroll
    for (int r = 0; r < 8; r++) {
        int grow = rowBase + r0 + r;
        if (grow < nrows) {
            float sc = dinv[grow];
            uint4 o;
            unsigned w0a = f2bf(acc[r][0] * sc), w0b = f2bf(acc[r][1] * sc);
            unsigned w1a = f2bf(acc[r][2] * sc), w1b = f2bf(acc[r][3] * sc);
            unsigned w2a = f2bf(acc[r][4] * sc), w2b = f2bf(acc[r][5] * sc);
            unsigned w3a = f2bf(acc[r][6] * sc), w3b = f2bf(acc[r][7] * sc);
            o.x = w0a | (w0b << 16);
            o.y = w1a | (w1b << 16);
            o.z = w2a | (w2b << 16);
            o.w = w3a | (w3b << 16);
            *(uint4*)&out[(size_t)grow * 64 + c0] = o;
        }
    }
}

// ---- aggregation: one wave per node, lane = feature column ----------------
// out[n] = dinv[n] * (hs[n] + sum_{e in adj(n)} hs[col[e]]) + bias
// hs is bf16 (128B/row gather); accumulation in f32.
__global__ __launch_bounds__(256) void aggregate_kernel(
        const ushort_t* __restrict__ hs, const float* __restrict__ dinv,
        const float* __restrict__ bias, const int* __restrict__ col,
        const int* __restrict__ row_ptr, const float* __restrict__ resid,
        float* __restrict__ out, int n, int relu) {
    int wave = (blockIdx.x * blockDim.x + threadIdx.x) >> 6;
    int lane = threadIdx.x & 63;
    if (wave >= n) return;
    int start = row_ptr[wave];
    int end = row_ptr[wave + 1];
    float acc = bf2f(hs[(size_t)wave * 64 + lane]); // self-loop (pre-scaled)
    int e = start;
    while (e < end) {
        int cnt = end - e;
        if (cnt > 64) cnt = 64;
        int myidx = (lane < cnt) ? col[e + lane] : 0;
        int j = 0;
        for (; j + 8 <= cnt; j += 8) {
            int s0 = __shfl(myidx, j + 0);
            int s1 = __shfl(myidx, j + 1);
            int s2 = __shfl(myidx, j + 2);
            int s3 = __shfl(myidx, j + 3);
            int s4 = __shfl(myidx, j + 4);
            int s5 = __shfl(myidx, j + 5);
            int s6 = __shfl(myidx, j + 6);
            int s7 = __shfl(myidx, j + 7);
            ushort_t u0 = hs[(size_t)s0 * 64 + lane];
            ushort_t u1 = hs[(size_t)s1 * 64 + lane];
            ushort_t u2 = hs[(size_t)s2 * 64 + lane];
            ushort_t u3 = hs[(size_t)s3 * 64 + lane];
            ushort_t u4 = hs[(size_t)s4 * 64 + lane];
            ushort_t u5 = hs[(size_t)s5 * 64 + lane];
            ushort_t u6 = hs[(size_t)s6 * 64 + lane];
            ushort_t u7 = hs[(size_t)s7 * 64 + lane];
            acc += bf2f(u0) + bf2f(u1) + bf2f(u2) + bf2f(u3)
                 + bf2f(u4) + bf2f(u5) + bf2f(u6) + bf2f(u7);
        }
        for (; j < cnt; j++) {
            int s = __shfl(myidx, j);
            acc += bf2f(hs[(size_t)s * 64 + lane]);
        }
        e += cnt;
    }
    float o = dinv[wave] * acc + bias[lane];
    if (relu) o = fmaxf(o, 0.f);
    if (resid) o += resid[(size_t)wave * 64 + lane];
    out[(size_t)wave * 64 + lane] = o;
}

// ---------------------------------------------------------------------------
extern "C" void kernel_launch(void* const* d_in, const int* in_sizes, int n_in,
                              void* d_out, int out_size, void* d_ws, size_t ws_size,
                              hipStream_t stream) {
    const float* x  = (const float*)d_in[0];
    const int*   ei = (const int*)d_in[1];
    const float* W0 = (const float*)d_in[2];
    const float* b0 = (const float*)d_in[3];
    const float* Ws = (const float*)d_in[4];
    const float* bs = (const float*)d_in[5];
    float* out = (float*)d_out;

    const int N = in_sizes[0] / 128;
    const int E = in_sizes[1] / 2;
    const int B = (N + BKN - 1) >> LB;   // 391 buckets for N=100k

    char* p = (char*)d_ws;
    auto carve = [&](size_t bytes) {
        char* r = p;
        p += (bytes + 255) & ~(size_t)255;
        return r;
    };
    int*      flag         = (int*)carve(4);
    int*      bucketCounts = (int*)carve(512 * 4);
    int*      bucketOffs   = (int*)carve(513 * 4);
    int*      bucketCursor = (int*)carve(512 * 4);
    unsigned* packed       = (unsigned*)carve((size_t)E * 4);
    int*      col          = (int*)carve((size_t)E * 4);
    int*      row_ptr      = (int*)carve((size_t)(N + 1) * 4);
    float*    dinv         = (float*)carve((size_t)N * 4);
    ushort_t* hs           = (ushort_t*)carve((size_t)N * 64 * 2);
    float*    xt           = (float*)carve((size_t)N * 64 * 4);
    float*    h            = (float*)carve((size_t)N * 64 * 4);

    hipMemsetAsync(flag, 1, 4, stream);              // nonzero = "int64"
    hipMemsetAsync(bucketCounts, 0, 512 * 4, stream);

    int dwords = min(2 * E, 65536);                  // sampled dtype probe
    detect64_kernel<<<(dwords + 255) / 256, 256, 0, stream>>>(
        (const unsigned int*)ei, dwords, flag);

    bucket_hist_kernel<<<512, 256, 0, stream>>>(ei, E, flag, bucketCounts, B);
    bucket_scan_kernel<<<1, 512, 0, stream>>>(bucketCounts, bucketOffs, bucketCursor, B);
    bucket_scatter_kernel<<<(E + CHUNK - 1) / CHUNK, 256, 0, stream>>>(
        ei, flag, bucketCursor, packed, E);
    sort_kernel<<<B, 256, 0, stream>>>(packed, bucketOffs, col, row_ptr, dinv, N, E);

    int gblocks = (N + 255) / 256;
    int ablocks = (N + 3) / 4;
    // layer 1: x_temp = agg(x @ W0) + b0            (no relu)
    gemm_scaled_kernel<128><<<gblocks, 256, 0, stream>>>(x, W0, dinv, hs, N);
    aggregate_kernel<<<ablocks, 256, 0, stream>>>(hs, dinv, b0, col, row_ptr, nullptr, xt, N, 0);
    // layer 2: h = relu(agg(xt @ Ws[0]) + bs[0])
    gemm_scaled_kernel<64><<<gblocks, 256, 0, stream>>>(xt, Ws, dinv, hs, N);
    aggregate_kernel<<<ablocks, 256, 0, stream>>>(hs, dinv, bs, col, row_ptr, nullptr, h, N, 1);
    // layer 3: out = relu(agg(h @ Ws[1]) + bs[1]) + xt
    gemm_scaled_kernel<64><<<gblocks, 256, 0, stream>>>(h, Ws + 64 * 64, dinv, hs, N);
    aggregate_kernel<<<ablocks, 256, 0, stream>>>(hs, dinv, bs + 64, col, row_ptr, xt, out, N, 1);
}